// Round 7
// baseline (267.276 us; speedup 1.0000x reference)
//
#include <hip/hip_runtime.h>

// BatchedCauchyKernel3d: out[b,i,j] = 1 / (1 + d/sqrt(scx[b,i]*scy[b,j]))
// d = clip(|x_i|^2 + |y_j|^2 - 2 x_i.y_j, 1e-10, 1e6)
// scx = clip(sample_x . clip(scale,1e-6,1e6), 1e-10, 1e6); likewise scy.
// Identities:
//   1/(1+d/s) == s/(s+d)                       -> one rcp per element
//   sqrt(clip(scx*scy,1e-10,1e12)) == max(sqrt(scx)*sqrt(scy), 1e-5)
// Structure (R6 resubmit — prior round was an infra failure, no data):
// two-pass. Main = ROW-STREAMING persistent blocks: 1024 blocks, each owns
// 16 CONSECUTIVE rows (262KB contiguous) of one batch and writes them in
// strictly ascending address order. Per-thread y-side cached in registers
// for the whole block (one batch per block -> load once); per-row x-side is
// a block-uniform scalar load. Low occupancy (~16 waves/CU) + long
// sequential per-block write streams = fill-like DRAM page locality (the
// fill hits 6.5 TB/s at 10% occupancy; all scattered-burst variants stuck
// at ~3.9 TB/s).

constexpr int kB  = 4;
constexpr int kNX = 4096;
constexpr int kNY = 4096;
constexpr int kF  = 16;
constexpr int kRowsPerBlk = 16;
constexpr int kMainBlks = kB * kNX / kRowsPerBlk;   // 1024

// ---------------- pre-pass: per-point (|p|^2, sqrt(clipped scale-dot)) ------
__global__ __launch_bounds__(256) void row_stats_kernel(
    const float* __restrict__ x, const float* __restrict__ y,
    const float* __restrict__ sx, const float* __restrict__ sy,
    const float* __restrict__ scale,
    float2* __restrict__ rx, float2* __restrict__ ry, int nper)
{
    int t = blockIdx.x * blockDim.x + threadIdx.x;
    if (t >= 2 * nper) return;
    const float* pts; const float* smp; float2* dst; int idx;
    if (t < nper) { pts = x; smp = sx; dst = rx; idx = t; }
    else          { pts = y; smp = sy; dst = ry; idx = t - nper; }

    const float* p = pts + (size_t)idx * 3;
    float sq = p[0] * p[0] + p[1] * p[1] + p[2] * p[2];

    const float4* s4 = (const float4*)(smp + (size_t)idx * kF);
    const float4* c4 = (const float4*)scale;
    float acc = 0.f;
#pragma unroll
    for (int k = 0; k < kF / 4; ++k) {
        float4 sv = s4[k];
        float4 cv = c4[k];
        acc += sv.x * fminf(fmaxf(cv.x, 1e-6f), 1e6f);
        acc += sv.y * fminf(fmaxf(cv.y, 1e-6f), 1e6f);
        acc += sv.z * fminf(fmaxf(cv.z, 1e-6f), 1e6f);
        acc += sv.w * fminf(fmaxf(cv.w, 1e-6f), 1e6f);
    }
    float sc = fminf(fmaxf(acc, 1e-10f), 1e6f);
    dst[idx] = make_float2(sq, __builtin_amdgcn_sqrtf(sc));
}

// ---------------- main: row-streaming, 16 consecutive rows per block --------
// blk -> b = blk>>8, row0 = (blk&255)*16. Thread t owns 4 column groups
// j0(s) = (s*256+t)*4; y-side for those 16 points cached in ~80 VGPRs.
// Row loop: block-uniform scalar x/rx load, 16 outputs/thread, 4 float4
// stores per row per thread. Block writes 262KB in ascending address order.
__global__ __launch_bounds__(256, 2) void cauchy_main_kernel(
    const float* __restrict__ x, const float* __restrict__ y,
    const float2* __restrict__ rx, const float2* __restrict__ ry,
    float* __restrict__ out)
{
    const int blk  = blockIdx.x;                 // 0..1023
    const int b    = blk >> 8;                   // 0..3
    const int row0 = (blk & 255) * kRowsPerBlk;  // 0..4080
    const int t    = threadIdx.x;                // 0..255

    // y-side register cache: s = column group, k = point within group
    float yxx[4][4], yyy[4][4], yzz[4][4], sqy[4][4], scy[4][4];
#pragma unroll
    for (int s = 0; s < 4; ++s) {
        const int j0 = ((s << 8) | t) << 2;
        const float4* yv = (const float4*)(y + ((size_t)b * kNY + j0) * 3);
        float4 ya = yv[0], yb = yv[1], yc = yv[2];
        const float4* ryv = (const float4*)(ry + (size_t)b * kNY + j0);
        float4 r01 = ryv[0], r23 = ryv[1];
        yxx[s][0] = ya.x; yxx[s][1] = ya.w; yxx[s][2] = yb.z; yxx[s][3] = yc.y;
        yyy[s][0] = ya.y; yyy[s][1] = yb.x; yyy[s][2] = yb.w; yyy[s][3] = yc.z;
        yzz[s][0] = ya.z; yzz[s][1] = yb.y; yzz[s][2] = yc.x; yzz[s][3] = yc.w;
        sqy[s][0] = r01.x; sqy[s][1] = r01.z; sqy[s][2] = r23.x; sqy[s][3] = r23.z;
        scy[s][0] = r01.y; scy[s][1] = r01.w; scy[s][2] = r23.y; scy[s][3] = r23.w;
    }

#pragma unroll 2
    for (int r = 0; r < kRowsPerBlk; ++r) {
        const int i = row0 + r;
        // block-uniform -> scalar loads
        const float* xp = x + ((size_t)b * kNX + i) * 3;
        const float xx = xp[0], xy = xp[1], xz = xp[2];
        const float2 st = rx[(size_t)b * kNX + i];
        const float sqx = st.x, scx = st.y;

        const size_t rowbase = ((size_t)b * kNX + i) * (size_t)kNY;
#pragma unroll
        for (int s = 0; s < 4; ++s) {
            const int j0 = ((s << 8) | t) << 2;
            float4 o;
            float* op = (float*)&o;
#pragma unroll
            for (int k = 0; k < 4; ++k) {
                float dot = xx * yxx[s][k] + xy * yyy[s][k] + xz * yzz[s][k];
                float d = fmaf(-2.f, dot, sqx + sqy[s][k]);
                d = fminf(fmaxf(d, 1e-10f), 1e6f);
                float sc = fmaxf(scx * scy[s][k], 1e-5f);
                op[k] = sc * __builtin_amdgcn_rcpf(sc + d);
            }
            *(float4*)(out + rowbase + j0) = o;
        }
    }
}

// ---------------- fallback (ws too small): fully fused, correct -------------
__global__ __launch_bounds__(256) void cauchy_fallback_kernel(
    const float* __restrict__ x, const float* __restrict__ y,
    const float* __restrict__ sx, const float* __restrict__ sy,
    const float* __restrict__ scale, float* __restrict__ out)
{
    const int t = blockIdx.x * 256 + threadIdx.x;
    const int jc = t & (kNY / 4 - 1);
    const int rowtile = t >> 10;
    const int b  = rowtile >> 10;
    const int i0 = (rowtile & (kNX / 4 - 1)) << 2;
    const int j0 = jc << 2;

    float4 c[4];
    const float4* c4 = (const float4*)scale;
#pragma unroll
    for (int k = 0; k < 4; ++k) {
        float4 cv = c4[k];
        c[k].x = fminf(fmaxf(cv.x, 1e-6f), 1e6f);
        c[k].y = fminf(fmaxf(cv.y, 1e-6f), 1e6f);
        c[k].z = fminf(fmaxf(cv.z, 1e-6f), 1e6f);
        c[k].w = fminf(fmaxf(cv.w, 1e-6f), 1e6f);
    }

    const float4* yv = (const float4*)(y + ((size_t)b * kNY + j0) * 3);
    float4 ya = yv[0], yb = yv[1], yc = yv[2];
    const float4* xv = (const float4*)(x + ((size_t)b * kNX + i0) * 3);
    float4 xa = xv[0], xb = xv[1], xc = xv[2];

    const float yxx[4] = {ya.x, ya.w, yb.z, yc.y};
    const float yyy[4] = {ya.y, yb.x, yb.w, yc.z};
    const float yzz[4] = {ya.z, yb.y, yc.x, yc.w};
    const float xxx[4] = {xa.x, xa.w, xb.z, xc.y};
    const float xyy[4] = {xa.y, xb.x, xb.w, xc.z};
    const float xzz[4] = {xa.z, xb.y, xc.x, xc.w};

    float sqx[4], scx[4], sqy[4], scy[4];
#pragma unroll
    for (int r = 0; r < 4; ++r) {
        sqx[r] = xxx[r] * xxx[r] + xyy[r] * xyy[r] + xzz[r] * xzz[r];
        sqy[r] = yxx[r] * yxx[r] + yyy[r] * yyy[r] + yzz[r] * yzz[r];
        const float4* a4 = (const float4*)(sx + ((size_t)b * kNX + i0 + r) * kF);
        const float4* b4 = (const float4*)(sy + ((size_t)b * kNY + j0 + r) * kF);
        float accx = 0.f, accy = 0.f;
#pragma unroll
        for (int k = 0; k < 4; ++k) {
            float4 av = a4[k], bv = b4[k], cv = c[k];
            accx += av.x * cv.x + av.y * cv.y + av.z * cv.z + av.w * cv.w;
            accy += bv.x * cv.x + bv.y * cv.y + bv.z * cv.z + bv.w * cv.w;
        }
        scx[r] = __builtin_amdgcn_sqrtf(fminf(fmaxf(accx, 1e-10f), 1e6f));
        scy[r] = __builtin_amdgcn_sqrtf(fminf(fmaxf(accy, 1e-10f), 1e6f));
    }

    size_t obase = ((size_t)b * kNX + i0) * (size_t)kNY + j0;
#pragma unroll
    for (int r = 0; r < 4; ++r) {
        float4 o;
        float* op = (float*)&o;
#pragma unroll
        for (int k = 0; k < 4; ++k) {
            float dot = xxx[r] * yxx[k] + xyy[r] * yyy[k] + xzz[r] * yzz[k];
            float d = fmaf(-2.f, dot, sqx[r] + sqy[k]);
            d = fminf(fmaxf(d, 1e-10f), 1e6f);
            float s = fmaxf(scx[r] * scy[k], 1e-5f);
            op[k] = s * __builtin_amdgcn_rcpf(s + d);
        }
        *(float4*)(out + obase + (size_t)r * kNY) = o;
    }
}

extern "C" void kernel_launch(void* const* d_in, const int* in_sizes, int n_in,
                              void* d_out, int out_size, void* d_ws, size_t ws_size,
                              hipStream_t stream) {
    const float* x     = (const float*)d_in[0];
    const float* y     = (const float*)d_in[1];
    const float* sx    = (const float*)d_in[2];
    const float* sy    = (const float*)d_in[3];
    const float* scale = (const float*)d_in[4];
    float* out = (float*)d_out;

    const int nper = kB * kNX;                              // 16384 points/side
    const size_t need = (size_t)2 * nper * sizeof(float2);  // 256 KiB

    if (ws_size >= need) {
        float2* rx = (float2*)d_ws;
        float2* ry = rx + nper;
        row_stats_kernel<<<(2 * nper + 255) / 256, 256, 0, stream>>>(
            x, y, sx, sy, scale, rx, ry, nper);
        cauchy_main_kernel<<<kMainBlks, 256, 0, stream>>>(x, y, rx, ry, out);
    } else {
        const int fb_blocks = (kB * kNX * kNY / 16) / 256;  // 16384
        cauchy_fallback_kernel<<<fb_blocks, 256, 0, stream>>>(
            x, y, sx, sy, scale, out);
    }
}